// Round 8
// baseline (56.847 us; speedup 1.0000x reference)
//
#include <hip/hip_runtime.h>
#include <hip/hip_bf16.h>

// Taylor attention v8: ILP-first modulo schedule. 512 uniform blocks (130
// steps each: strips pp, 63-pp, 16+pp, 47-pp), exactly 2 blocks/CU (forced by
// 66KB LDS), 256-VGPR budget. Per-step pipeline: QK MFMA for step n+1 issues
// before poly(n); K/V register-double-buffered one body ahead; hoisted ZERO
// C-operand; 4-way Z partials. fp16 QK^T, RNE-bf16 PV (as v7).

typedef __attribute__((ext_vector_type(8))) short bf16x8;
typedef __attribute__((ext_vector_type(8))) _Float16 f16x8;
typedef __attribute__((ext_vector_type(4))) float f32x4;
typedef __attribute__((ext_vector_type(16))) float f32x16;
typedef unsigned int u32;
typedef unsigned short u16;

namespace {

constexpr int T_SEQ = 2048;
constexpr int DK    = 32;
constexpr int DV    = 64;
constexpr int NBH   = 32;

// w = ((C3*s + C2)*s + C1)*s + 1  with s = raw dot (1/sqrt(32) folded in)
constexpr float C1 = 0.17677669529663687f;   // c
constexpr float C2 = 0.015625f;              // c^2/2 (exact)
constexpr float C3 = 9.2071195e-4f;          // c^3/6

// workspace layout (bytes): Khf (fp16) 4MiB | Vthi (bf16) 8MiB
constexpr size_t KHF_OFF  = 0;
constexpr size_t VTHI_OFF = (size_t)NBH * T_SEQ * DK * 2;             //  4 MiB
constexpr size_t WS_NEED  = VTHI_OFF + (size_t)NBH * DV * T_SEQ * 2;  // 12 MiB

__device__ __forceinline__ u32 pack_hi2(float f0, float f1) {
  return (__float_as_uint(f0) >> 16) | (__float_as_uint(f1) & 0xffff0000u);
}
__device__ __forceinline__ float trunc_bf(float f) {
  return __uint_as_float(__float_as_uint(f) & 0xffff0000u);
}
__device__ __forceinline__ u16 f2h(float f) {
  union { _Float16 h; u16 u; } c;
  c.h = (_Float16)f;             // RNE
  return c.u;
}
// RNE bf16 pair pack (compiler lowers to v_cvt_pk_bf16_f32)
__device__ __forceinline__ u32 pack_rn2(float f0, float f1) {
  union { __hip_bfloat16 h; u16 u; } a, b;
  a.h = __hip_bfloat16(f0);
  b.h = __hip_bfloat16(f1);
  return (u32)a.u | ((u32)b.u << 16);
}
// Swap a.lanes[32:63] <-> b.lanes[0:31].
__device__ __forceinline__ void permswap(u32& a, u32& b) {
  asm volatile("v_permlane32_swap_b32 %0, %1" : "+v"(a), "+v"(b));
}

// ---------------- pack kernel (K -> fp16; V^T -> RNE bf16) ----------------

__global__ void pack_kv(const float* __restrict__ Kg, const float* __restrict__ Vg,
                        u16* __restrict__ Khf, u16* __restrict__ Vthi) {
  __shared__ float tile[DV][33];
  const int bid = blockIdx.x;
  const int t   = threadIdx.x;
  if (bid < 2048) {  // ---- K: elementwise fp16 convert
    size_t i = ((size_t)bid * 256 + t) * 4;
    float4 f = *(const float4*)(Kg + i);
    ushort4 h;
    h.x = f2h(f.x); h.y = f2h(f.y); h.z = f2h(f.z); h.w = f2h(f.w);
    *(ushort4*)(Khf + i) = h;
  } else {           // ---- V: transpose 32k x 64c tiles, RNE bf16
    const int vb = bid - 2048;
    const int bh = vb >> 6;
    const int k0 = (vb & 63) * 32;
    {
      const int kl = t >> 3, c0 = (t & 7) * 8;
      const float* src = Vg + ((size_t)bh * T_SEQ + k0 + kl) * DV + c0;
      float4 a = *(const float4*)src;
      float4 b = *(const float4*)(src + 4);
      tile[c0 + 0][kl] = a.x; tile[c0 + 1][kl] = a.y;
      tile[c0 + 2][kl] = a.z; tile[c0 + 3][kl] = a.w;
      tile[c0 + 4][kl] = b.x; tile[c0 + 5][kl] = b.y;
      tile[c0 + 6][kl] = b.z; tile[c0 + 7][kl] = b.w;
    }
    __syncthreads();
    {
      const int cl = t >> 2, k8 = (t & 3) * 8;
      u32 h[4];
#pragma unroll
      for (int j = 0; j < 4; ++j)
        h[j] = pack_rn2(tile[cl][k8 + 2 * j], tile[cl][k8 + 2 * j + 1]);
      size_t off = ((size_t)(bh * DV + cl)) * T_SEQ + k0 + k8;
      *(uint4*)(Vthi + off) = make_uint4(h[0], h[1], h[2], h[3]);
    }
  }
}

// ---------------- main kernel (v8) ----------------

__global__ __launch_bounds__(256, 2)
void taylor_attn_v8(const float* __restrict__ Qg, const u16* __restrict__ Khf,
                    const u16* __restrict__ Vthi, float* __restrict__ Outg) {
  // double-buffered across phases: 2 x 32KB (+Zp) = 66KB -> exactly 2 blocks/CU
  __shared__ __align__(16) float Sp[2][4 * 2048];
  __shared__ float Zp[2][4 * 32];

  const int tid = threadIdx.x;
  const int l   = tid & 63;
  const int w   = tid >> 6;
  const int cq  = l & 31;
  const int hi  = l >> 5;

  // decode: 8 XCDs x 4 bh x 16 quad-groups; block = strips {pp,63-pp,16+pp,47-pp}
  // = 130 steps, uniform for every block.
  const int bid = blockIdx.x;
  const int xcd = bid & 7;
  const int r_  = bid >> 3;            // 0..63
  const int bh  = xcd * 4 + (r_ & 3);
  const int pp  = r_ >> 2;             // 0..15

  const u16* kq = Khf + (size_t)bh * T_SEQ * DK + (size_t)cq * DK + hi * 8;
  const u16* vq = Vthi + (size_t)bh * DV * T_SEQ + (size_t)cq * T_SEQ + hi * 8;
  const float* qb = Qg + (size_t)bh * T_SEQ * DK;

  f32x16 ZERO;
#pragma unroll
  for (int r = 0; r < 16; ++r) ZERO[r] = 0.f;

#pragma unroll 1
  for (int ph = 0; ph < 4; ++ph) {
    const int s  = (ph == 0) ? pp : (ph == 1) ? (63 - pp)
                 : (ph == 2) ? (16 + pp) : (47 - pp);
    const int q0 = s * 32;
    float* SpH = &Sp[ph & 1][0];
    float* ZpH = &Zp[ph & 1][0];

    // ---- Q B-fragments, fp16 RNE
    f16x8 qf[2];
#pragma unroll
    for (int t = 0; t < 2; ++t) {
      const float* qp = qb + (size_t)(q0 + cq) * DK + t * 16 + hi * 8;
      float4 a = *(const float4*)qp;
      float4 b = *(const float4*)(qp + 4);
      f16x8 v;
      v[0] = (_Float16)a.x; v[1] = (_Float16)a.y;
      v[2] = (_Float16)a.z; v[3] = (_Float16)a.w;
      v[4] = (_Float16)b.x; v[5] = (_Float16)b.y;
      v[6] = (_Float16)b.z; v[7] = (_Float16)b.w;
      qf[t] = v;
    }

    f32x16 acc0 = ZERO, acc1 = ZERO;
    float zpa = 0.f, zpb = 0.f, zpc = 0.f, zpd = 0.f;

    auto LOADK = [&](f16x8* kf, int kt) {
      const u16* kp = kq + (size_t)kt * 1024;
      kf[0] = *(const f16x8*)kp;
      kf[1] = *(const f16x8*)(kp + 16);
    };
    auto LOADV = [&](bf16x8* vf, int kt) {
#pragma unroll
      for (int ct = 0; ct < 2; ++ct)
#pragma unroll
        for (int t = 0; t < 2; ++t)
          vf[ct * 2 + t] = *(const bf16x8*)(
              vq + (size_t)ct * 32 * T_SEQ + kt * 32 + t * 16);
    };
    auto QK = [&](const f16x8* kf) -> f32x16 {
      f32x16 d = __builtin_amdgcn_mfma_f32_32x32x16_f16(kf[0], qf[0], ZERO, 0, 0, 0);
      return __builtin_amdgcn_mfma_f32_32x32x16_f16(kf[1], qf[1], d, 0, 0, 0);
    };
    auto FINISH = [&](const f32x16& d, const bf16x8* vf, bool diag) {
      float wv[16];
#pragma unroll
      for (int r = 0; r < 16; ++r) {
        float sc = d[r];
        float t_ = __builtin_fmaf(sc, C3, C2);
        t_       = __builtin_fmaf(sc, t_, C1);
        float wr = __builtin_fmaf(sc, t_, 1.0f);
        if (diag) {
          const int krel = (r & 3) + 8 * (r >> 2) + 4 * hi;
          wr = (krel <= cq) ? wr : 0.f;
        }
        wv[r] = wr;
      }
      zpa += (wv[0] + wv[4]) + (wv[8]  + wv[12]);
      zpb += (wv[1] + wv[5]) + (wv[9]  + wv[13]);
      zpc += (wv[2] + wv[6]) + (wv[10] + wv[14]);
      zpd += (wv[3] + wv[7]) + (wv[11] + wv[15]);
      union { bf16x8 v; u32 u[4]; } WH[2];
#pragma unroll
      for (int t = 0; t < 2; ++t) {
        const int b = t * 8;
        u32 p0 = pack_rn2(wv[b + 0], wv[b + 1]);
        u32 p1 = pack_rn2(wv[b + 2], wv[b + 3]);
        u32 p2 = pack_rn2(wv[b + 4], wv[b + 5]);
        u32 p3 = pack_rn2(wv[b + 6], wv[b + 7]);
        permswap(p0, p2); permswap(p1, p3);
        WH[t].u[0] = p0; WH[t].u[1] = p1; WH[t].u[2] = p2; WH[t].u[3] = p3;
      }
      acc0 = __builtin_amdgcn_mfma_f32_32x32x16_bf16(WH[0].v, vf[0], acc0, 0, 0, 0);
      acc0 = __builtin_amdgcn_mfma_f32_32x32x16_bf16(WH[1].v, vf[1], acc0, 0, 0, 0);
      acc1 = __builtin_amdgcn_mfma_f32_32x32x16_bf16(WH[0].v, vf[2], acc1, 0, 0, 0);
      acc1 = __builtin_amdgcn_mfma_f32_32x32x16_bf16(WH[1].v, vf[3], acc1, 0, 0, 0);
    };

    // ---- pipelined main loop (kt < s, mask-free), modulo schedule:
    //      body n: QK(n+1) issues before poly(n); K/V prefetched a body ahead.
    {
      int kt = w;
      if (kt < s) {
        f16x8 kA[2], kB[2];
        bf16x8 vA[4], vB[4];
        f32x16 dA, dB;
        LOADK(kA, kt);
        LOADV(vA, kt);
        int kn = kt + 4;
        bool haveB = (kn < s);
        if (haveB) { LOADK(kB, kn); LOADV(vB, kn); }
        dA = QK(kA);
        while (true) {
          // ---- body A: cur=(dA,vA)@kt, next=(kB,vB)@kn
          if (!haveB) { FINISH(dA, vA, false); break; }
          dB = QK(kB);
          { int k2 = kn + 4; if (k2 < s) LOADK(kA, k2); }
          FINISH(dA, vA, false);
          { int k2 = kn + 4; if (k2 < s) LOADV(vA, k2); }
          kt = kn; kn = kt + 4; haveB = (kn < s);
          // ---- body B: cur=(dB,vB)@kt, next=(kA,vA)@kn
          if (!haveB) { FINISH(dB, vB, false); break; }
          dA = QK(kA);
          { int k2 = kn + 4; if (k2 < s) LOADK(kB, k2); }
          FINISH(dB, vB, false);
          { int k2 = kn + 4; if (k2 < s) LOADV(vB, k2); }
          kt = kn; kn = kt + 4; haveB = (kn < s);
        }
      }
    }
    // ---- peeled diagonal step (owner wave only, masked)
    if ((s & 3) == w) {
      f16x8 kD[2]; LOADK(kD, s);
      bf16x8 vD[4]; LOADV(vD, s);
      f32x16 dD = QK(kD);
      FINISH(dD, vD, true);
    }

    // ---- publish Z + S partials
    {
      float zacc = (zpa + zpb) + (zpc + zpd);
      float zt = zacc + __shfl_xor(zacc, 32);
      if (hi == 0) ZpH[w * 32 + cq] = zt;
    }
#pragma unroll
    for (int r = 0; r < 16; ++r) {
      const int qr = (r & 3) + 8 * (r >> 2) + 4 * hi;
      SpH[w * 2048 + qr * 64 + cq]      = acc0[r];
      SpH[w * 2048 + qr * 64 + 32 + cq] = acc1[r];
    }
    __syncthreads();

    // ---- combine 4 slices + divide + store
    const f32x4* S4 = (const f32x4*)SpH;
#pragma unroll
    for (int i = 0; i < 2; ++i) {
      const int e4  = tid + i * 256;
      const int row = e4 >> 4;
      f32x4 ssum = S4[e4] + S4[512 + e4] + S4[1024 + e4] + S4[1536 + e4];
      float z = ZpH[row] + ZpH[32 + row] + ZpH[64 + row] + ZpH[96 + row];
      float inv = 1.0f / z;
      float4 o;
      o.x = ssum[0] * inv; o.y = ssum[1] * inv;
      o.z = ssum[2] * inv; o.w = ssum[3] * inv;
      *(float4*)(Outg + ((size_t)bh * T_SEQ + q0 + row) * DV + (e4 & 15) * 4) = o;
    }
    // no trailing barrier: next phase writes the other Sp half; the next
    // phase's pre-combine barrier orders reuse of this half (2-phase distance).
  }
}

// ---------------- fallback (no workspace): v2 staged-LDS kernel ----------------

constexpr int QT_FB = 64;
constexpr int KT_FB = 32;
constexpr int LDSW  = 40;
constexpr float SCALE = 0.17677669529663687f;

__global__ __launch_bounds__(256, 4)
void taylor_attn_fb(const float* __restrict__ Qg, const float* __restrict__ Kg,
                    const float* __restrict__ Vg, float* __restrict__ Outg) {
  __shared__ __align__(16) unsigned short Qhi[QT_FB * LDSW], Qlo[QT_FB * LDSW];
  __shared__ __align__(16) unsigned short Khi_[KT_FB * LDSW], Klo_[KT_FB * LDSW];
  __shared__ __align__(16) unsigned short Vthi_[DV * LDSW], Vtlo_[DV * LDSW];
  __shared__ __align__(16) unsigned Wp[4][16 * 32];

  const int tid  = threadIdx.x;
  const int lane = tid & 63;
  const int wid  = tid >> 6;
  const int m    = lane & 15;
  const int g    = lane >> 4;

  const int bid = blockIdx.x;
  const int v   = bid >> 3;
  const int bh  = (bid & 7) * 4 + (v >> 5);
  const int qt  = 31 - (v & 31);
  const int q0  = qt * QT_FB;

  const float* Qbase = Qg + ((size_t)bh * T_SEQ + q0) * DK;
  const float* Kbase = Kg + (size_t)bh * T_SEQ * DK;
  const float* Vbase = Vg + (size_t)bh * T_SEQ * DV;

#pragma unroll
  for (int p = 0; p < 2; ++p) {
    int e = tid + p * 256, row = e >> 3, c4 = (e & 7) * 4;
    float4 f = *(const float4*)(Qbase + row * DK + c4);
    uint2 h, l;
    h.x = pack_hi2(f.x, f.y); h.y = pack_hi2(f.z, f.w);
    l.x = pack_hi2(f.x - trunc_bf(f.x), f.y - trunc_bf(f.y));
    l.y = pack_hi2(f.z - trunc_bf(f.z), f.w - trunc_bf(f.w));
    *(uint2*)&Qhi[row * LDSW + c4] = h;
    *(uint2*)&Qlo[row * LDSW + c4] = l;
  }
  __syncthreads();

  const int wq = wid * 16;
  const bf16x8 qhi = *(const bf16x8*)&Qhi[(wq + m) * LDSW + g * 8];
  const bf16x8 qlo = *(const bf16x8*)&Qlo[(wq + m) * LDSW + g * 8];

  f32x4 acc[4];
#pragma unroll
  for (int ct = 0; ct < 4; ++ct) acc[ct] = f32x4{0.f, 0.f, 0.f, 0.f};
  float zacc[4] = {0.f, 0.f, 0.f, 0.f};

  const int q_lane0 = q0 + wq + g * 4;
  const int q_wave_max = q0 + wq + 15;

  const int nkt = (q0 + QT_FB) / KT_FB;
  for (int kt = 0; kt < nkt; ++kt) {
    const int k0 = kt * KT_FB;
    __syncthreads();
    {
      int row = tid >> 3, c4 = (tid & 7) * 4;
      float4 f = *(const float4*)(Kbase + (size_t)(k0 + row) * DK + c4);
      uint2 h, l;
      h.x = pack_hi2(f.x, f.y); h.y = pack_hi2(f.z, f.w);
      l.x = pack_hi2(f.x - trunc_bf(f.x), f.y - trunc_bf(f.y));
      l.y = pack_hi2(f.z - trunc_bf(f.z), f.w - trunc_bf(f.w));
      *(uint2*)&Khi_[row * LDSW + c4] = h;
      *(uint2*)&Klo_[row * LDSW + c4] = l;
    }
    {
      int kk = (tid & 15) * 2, c4 = (tid >> 4) * 4;
      const float* vp = Vbase + (size_t)(k0 + kk) * DV + c4;
      float4 a = *(const float4*)vp;
      float4 b = *(const float4*)(vp + DV);
      float af[4] = {a.x, a.y, a.z, a.w};
      float bf_[4] = {b.x, b.y, b.z, b.w};
#pragma unroll
      for (int jj = 0; jj < 4; ++jj) {
        *(unsigned*)&Vthi_[(c4 + jj) * LDSW + kk] = pack_hi2(af[jj], bf_[jj]);
        *(unsigned*)&Vtlo_[(c4 + jj) * LDSW + kk] =
            pack_hi2(af[jj] - trunc_bf(af[jj]), bf_[jj] - trunc_bf(bf_[jj]));
      }
    }
    __syncthreads();

    if (k0 > q_wave_max) continue;

#pragma unroll
    for (int k16 = 0; k16 < 2; ++k16) {
      const int kcol0 = k16 * 16;
      bf16x8 khi = *(const bf16x8*)&Khi_[(kcol0 + m) * LDSW + g * 8];
      bf16x8 klo = *(const bf16x8*)&Klo_[(kcol0 + m) * LDSW + g * 8];
      f32x4 sc = {0.f, 0.f, 0.f, 0.f};
      sc = __builtin_amdgcn_mfma_f32_16x16x32_bf16(qhi, khi, sc, 0, 0, 0);
      sc = __builtin_amdgcn_mfma_f32_16x16x32_bf16(qhi, klo, sc, 0, 0, 0);
      sc = __builtin_amdgcn_mfma_f32_16x16x32_bf16(qlo, khi, sc, 0, 0, 0);
      const int k_abs = k0 + kcol0 + m;
      const int kcol  = kcol0 + m;
#pragma unroll
      for (int r = 0; r < 4; ++r) {
        float x  = sc[r] * SCALE;
        float a3 = __builtin_fmaf(x, 0.3333333333333333f, 1.0f);
        float a2 = __builtin_fmaf(x * 0.5f, a3, 1.0f);
        float wvv = __builtin_fmaf(x, a2, 1.0f);
        wvv = (k_abs <= q_lane0 + r) ? wvv : 0.0f;
        zacc[r] += wvv;
        float wl = wvv - trunc_bf(wvv);
        unsigned packed = (__float_as_uint(wvv) >> 16) |
                          (__float_as_uint(wl) & 0xffff0000u);
        const int q = g * 4 + r;
        Wp[wid][q * 32 + (((kcol >> 2) ^ (q & 7)) << 2) + (kcol & 3)] = packed;
      }
    }

    uint4 pa = *(const uint4*)&Wp[wid][m * 32 + (((2 * g) ^ (m & 7)) << 2)];
    uint4 pb = *(const uint4*)&Wp[wid][m * 32 + (((2 * g + 1) ^ (m & 7)) << 2)];
    union { bf16x8 v; unsigned u[4]; } WH, WL;
    WH.u[0] = (pa.x & 0xffffu) | (pa.y << 16);
    WH.u[1] = (pa.z & 0xffffu) | (pa.w << 16);
    WH.u[2] = (pb.x & 0xffffu) | (pb.y << 16);
    WH.u[3] = (pb.z & 0xffffu) | (pb.w << 16);
    WL.u[0] = (pa.x >> 16) | (pa.y & 0xffff0000u);
    WL.u[1] = (pa.z >> 16) | (pa.w & 0xffff0000u);
    WL.u[2] = (pb.x >> 16) | (pb.y & 0xffff0000u);
    WL.u[3] = (pb.z >> 16) | (pb.w & 0xffff0000u);

#pragma unroll
    for (int ct = 0; ct < 4; ++ct) {
      bf16x8 vhi = *(const bf16x8*)&Vthi_[(ct * 16 + m) * LDSW + g * 8];
      bf16x8 vlo = *(const bf16x8*)&Vtlo_[(ct * 16 + m) * LDSW + g * 8];
      acc[ct] = __builtin_amdgcn_mfma_f32_16x16x32_bf16(WH.v, vhi, acc[ct], 0, 0, 0);
      acc[ct] = __builtin_amdgcn_mfma_f32_16x16x32_bf16(WH.v, vlo, acc[ct], 0, 0, 0);
      acc[ct] = __builtin_amdgcn_mfma_f32_16x16x32_bf16(WL.v, vhi, acc[ct], 0, 0, 0);
    }
  }

  float invz[4];
#pragma unroll
  for (int r = 0; r < 4; ++r) {
    float z = zacc[r];
    z += __shfl_xor(z, 1); z += __shfl_xor(z, 2);
    z += __shfl_xor(z, 4); z += __shfl_xor(z, 8);
    invz[r] = 1.0f / z;
  }

  float* ob = Outg + ((size_t)bh * T_SEQ + (q0 + wq)) * DV;
#pragma unroll
  for (int ct = 0; ct < 4; ++ct)
#pragma unroll
    for (int r = 0; r < 4; ++r)
      ob[(g * 4 + r) * DV + ct * 16 + m] = acc[ct][r] * invz[r];
}

}  // namespace

extern "C" void kernel_launch(void* const* d_in, const int* in_sizes, int n_in,
                              void* d_out, int out_size, void* d_ws, size_t ws_size,
                              hipStream_t stream) {
  const float* Q = (const float*)d_in[0];
  const float* K = (const float*)d_in[1];
  const float* V = (const float*)d_in[2];
  float* Out = (float*)d_out;

  if (ws_size >= WS_NEED && d_ws != nullptr) {
    u16* khf  = (u16*)((char*)d_ws + KHF_OFF);
    u16* vthi = (u16*)((char*)d_ws + VTHI_OFF);

    hipLaunchKernelGGL(pack_kv, dim3(4096), dim3(256), 0, stream, K, V, khf, vthi);
    hipLaunchKernelGGL(taylor_attn_v8, dim3(512), dim3(256), 0, stream,
                       Q, khf, vthi, Out);
  } else {
    hipLaunchKernelGGL(taylor_attn_fb, dim3(1024), dim3(256), 0, stream,
                       Q, K, V, Out);
  }
}